// Round 9
// baseline (879.240 us; speedup 1.0000x reference)
//
#include <hip/hip_runtime.h>

#define NLVL 16
#define NTOT 1846083
#define NTILE 2254
#define NBLOCK 564    // 4 wave-tiles per block (2 idle waves at the end)

typedef float  f32x4  __attribute__((ext_vector_type(4)));
typedef __bf16 bf16x8 __attribute__((ext_vector_type(8)));
typedef __bf16 bf16x4 __attribute__((ext_vector_type(4)));
typedef unsigned int u32;
typedef unsigned int u32x4 __attribute__((ext_vector_type(4)));

// level tables (static in reference)
__constant__ int c_R[NLVL]   = {16,18,20,22,25,27,30,34,38,42,47,52,58,64,72,80};
__constant__ int c_off[NLVL] = {0,4096,9928,17928,28576,44201,63884,90884,130188,185060,259148,362971,503579,698691,960835,1334083};
__constant__ int c_czy[NLVL] = {2,3,3,3,4,4,4,5,5,6,6,7,8,8,9,10};          // ceil(R/8)  (8-row wave tiles)
__constant__ int c_cx[NLVL]  = {1,2,2,2,2,2,2,3,3,3,3,4,4,4,5,5};           // ceil(R/16) (x-tiles = z-chunks)
// wave-tiles ordered level 15 -> 0 (longest first); count[l] = 2*czy*cx*cx
__constant__ int c_base[17]  = {0,500,950,1206,1462,1686,1794,1902,1992,2082,2114,2146,2178,2202,2226,2250,2254};

// weight fragments: [level][kz(3)][pair(5)][lane(64)][8 bf16] = 240 KB
__device__ __align__(16) unsigned short g_bfrag[NLVL*3*5*64*8];

// ---------------------------------------------------------------------------
// Pack weights into MFMA A-operand fragments (weights-as-A, data-as-B).
// A[m=co][k]: m=lane&15, k=(lane>>4)*8+j; k -> tip=k>>4, ci=k&15;
// in-plane tap t2 = 2*pair + tip (t2==9 padded with zero weight).
// ---------------------------------------------------------------------------
__global__ void prep_bfrag(const float* __restrict__ wgt) {
    int tid = blockIdx.x * 256 + threadIdx.x;
    if (tid >= NLVL*3*5*64) return;
    int lane = tid & 63;
    int p    = (tid >> 6) % 5;
    int d    = (tid / (5*64)) % 3;
    int l    = tid / (3*5*64);
    int quad = lane >> 4, co = lane & 15;
    unsigned short v[8];
#pragma unroll
    for (int j = 0; j < 8; ++j) {
        int k   = quad*8 + j;
        int tip = k >> 4;
        int ci  = k & 15;
        int t2  = 2*p + tip;
        float f = (t2 < 9) ? wgt[((l*27 + d*9 + t2)*16 + ci)*16 + co] : 0.f;
        v[j] = __builtin_bit_cast(unsigned short, (__bf16)f);
    }
    u32x4 pk;
    pk[0] = (u32)v[0] | ((u32)v[1] << 16);
    pk[1] = (u32)v[2] | ((u32)v[3] << 16);
    pk[2] = (u32)v[4] | ((u32)v[5] << 16);
    pk[3] = (u32)v[6] | ((u32)v[7] << 16);
    *(u32x4*)&g_bfrag[(size_t)tid*8] = pk;
}

// ---------------------------------------------------------------------------
// Barrier-free streaming-z conv, 16x * 8y per-wave tile, single-park staging.
// Per body: [cvt + ds_write plane parked last body -> ring(par^1)] ->
// [issue 12 f32x4 loads into the freed park regs] -> [40 ds_read_b128 ->
// 120 MFMA from ring(par) into 3 statically-renamed acc sets] -> [store the
// completed output plane]. Load->use window = 1 full body (~3000cy > HBM
// latency). No barriers; no acc-rotation moves (period-3 x ring-2 = 6-body
// macro unroll). All sync is compiler-counted waitcnt.
// ---------------------------------------------------------------------------
__global__ __launch_bounds__(256, 2)
void conv_kernel(const float* __restrict__ in,
                 const float* __restrict__ bias,
                 float* __restrict__ out) {
    // per-wave 12288B region: two bf16 planes [yp 0..9][xp 0..17][ci 0..15]
    // (5760B each) at +0 / +6144
    __shared__ __align__(16) char slab[4*12288];

    const int t    = threadIdx.x;
    const int lane = t & 63;
    const int wv   = t >> 6;

    // bijective XCD-aware swizzle (m204 variant, NBLOCK % 8 != 0)
    int bswz;
    {
        const int q = NBLOCK / 8, r = NBLOCK % 8;
        int xcd = blockIdx.x % 8, i = blockIdx.x / 8;
        bswz = (xcd < r ? xcd * (q + 1) : r * (q + 1) + (xcd - r) * q) + i;
    }

    const int tid4 = bswz*4 + wv;
    if (tid4 >= NTILE) return;    // safe: no barriers in this kernel
    int idx = 0;
#pragma unroll
    for (int i = 1; i < 16; ++i) if (tid4 >= c_base[i]) idx = i;
    const int l = 15 - idx;
    const int R = c_R[l], off = c_off[l], czy = c_czy[l], cx = c_cx[l];

    int local = tid4 - c_base[idx];
    int per_b = czy*cx*cx;
    int bb = local / per_b;         int r1 = local - bb*per_b;
    int zt = r1 / (czy*cx);         int r2 = r1 - zt*(czy*cx);
    int yt = r2 / cx;               int xt = r2 - yt*cx;
    const int z0 = zt*16;
    const int z1 = (z0 + 16 < R) ? z0 + 16 : R;
    const int y0 = yt*8, x0 = xt*16;
    const int steps = z1 - z0 + 2;

    const int quad = lane >> 4;
    const int m    = lane & 15;
    const int qh   = quad >> 1;

    // ---- weight fragments resident (15 x 16B per lane) ----
    bf16x8 bfr[15];
#pragma unroll
    for (int d = 0; d < 3; ++d)
#pragma unroll
        for (int p = 0; p < 5; ++p)
            bfr[d*5+p] = *(const bf16x8*)&g_bfrag[(size_t)(((l*3 + d)*5 + p)*64 + lane)*8];

    // ---- A-frag LDS base pointers (5 pairs; +PAR*6144 +r*576 folded as imm) ----
    const char* sbase = (const char*)slab + wv*12288;
    const char* arA[5];
    {
        const int T0[5] = {0, 64, 608, 1152, 1216};
        const int T1[5] = {32, 576, 640, 1184, 1216};
        const int ab = m*32 + (quad & 1)*16;
#pragma unroll
        for (int p = 0; p < 5; ++p) arA[p] = sbase + ab + (qh ? T1[p] : T0[p]);
    }
    char* wb = (char*)slab + wv*12288 + lane*8;

    // ---- staging: plane = 720 f32x4 chunks (10yp x 18xp x 4); 12 slots ----
    const int  zsE = R*R*16;            // f32 elements per z-plane
    const u32  zsB = (u32)zsE*4;        // bytes per z-plane
    const long gstartE = ((long)bb*NTOT + off)*16;

    u32 cur[12]; bool okk[12];
#pragma unroll
    for (int s = 0; s < 12; ++s) {
        int c = lane + s*64;
        int yp = c/72; int rem = c - yp*72; int xp = rem>>2; int ci4 = (rem&3)<<2;
        int y = y0 + yp - 1, x = x0 + xp - 1;
        okk[s] = (c < 720) && ((unsigned)y < (unsigned)R) && ((unsigned)x < (unsigned)R);
        long e = gstartE + (long)(z0-1)*zsE + ((long)y*R + x)*16 + ci4;
        cur[s] = (u32)(e*4);            // byte offset; only deref'd when guarded valid
    }
    const bool wr11 = (lane < 16);      // slot 11 valid chunks: c < 720

    const f32x4 z4 = {0,0,0,0};
    f32x4 LA[12];

    // ---- prologue ----
    {
        // load plane z0-1
        const bool zrA = (z0 > 0);
#pragma unroll
        for (int s = 0; s < 12; ++s) {
            f32x4 v = z4;
            if (zrA && okk[s]) v = *(const f32x4*)((const char*)in + cur[s]);
            LA[s] = v;
        }
#pragma unroll
        for (int s = 0; s < 12; ++s) cur[s] += zsB;
        // cvt + write plane z0-1 -> ring[0]
#pragma unroll
        for (int s = 0; s < 12; ++s) {
            if (s < 11 || wr11) {
                bf16x4 h = {(__bf16)LA[s][0],(__bf16)LA[s][1],(__bf16)LA[s][2],(__bf16)LA[s][3]};
                *(bf16x4*)(wb + s*512) = h;
            }
        }
        // load plane z0 (parked for body 0)
#pragma unroll
        for (int s = 0; s < 12; ++s) {
            f32x4 v = z4;
            if (okk[s]) v = *(const f32x4*)((const char*)in + cur[s]);
            LA[s] = v;
        }
#pragma unroll
        for (int s = 0; s < 12; ++s) cur[s] += zsB;
    }

    const bool xok = (x0 + m) < R;
    bool gr[8];
#pragma unroll
    for (int r = 0; r < 8; ++r) gr[r] = ((y0 + r) < R) && xok;
    const f32x4 bv4 = *(const f32x4*)(bias + (l << 4) + (quad << 2));
    const int rowE = R*16;              // f32 elements per output row

    // store base: plane z0-2 (advanced once per body; deref'd only when II>=2)
    float* so0 = out + gstartE + (((long)(z0-2)*R + y0)*(long)R + (x0 + m))*16 + (quad << 2);

    f32x4 c0[8], c1[8], c2[8];
#pragma unroll
    for (int r = 0; r < 8; ++r) { c0[r] = z4; c1[r] = z4; c2[r] = z4; }

    int zl = z0 + 1;   // plane loaded by body 0

    // Body II: writes parked plane (z0+II) -> ring[(II+1)&1]; loads plane
    // z0+1+II; MFMA plane z0-1+II from ring[II&1] (AX+=kz0 -> out plane+1,
    // AY+=kz1 -> out plane, AZ+=kz2 -> out plane-1 = completed); stores AZ.
#define BODY(II, PAR, AX, AY, AZ)                                                       \
    {                                                                                   \
        _Pragma("unroll")                                                               \
        for (int s = 0; s < 12; ++s) {                                                  \
            if (s < 11 || wr11) {                                                       \
                bf16x4 h = {(__bf16)LA[s][0],(__bf16)LA[s][1],(__bf16)LA[s][2],(__bf16)LA[s][3]}; \
                *(bf16x4*)(wb + ((PAR)^1)*6144 + s*512) = h;                            \
            }                                                                           \
        }                                                                               \
        {                                                                               \
            const bool zr = (zl <= z1) && (zl < R);                                     \
            _Pragma("unroll")                                                           \
            for (int s = 0; s < 12; ++s) {                                              \
                f32x4 v = z4;                                                           \
                if (zr && okk[s]) v = *(const f32x4*)((const char*)in + cur[s]);        \
                LA[s] = v;                                                              \
            }                                                                           \
            u32 a_ = zr ? zsB : 0u;                                                     \
            _Pragma("unroll")                                                           \
            for (int s = 0; s < 12; ++s) cur[s] += a_;                                  \
            ++zl;                                                                       \
        }                                                                               \
        _Pragma("unroll")                                                               \
        for (int p = 0; p < 5; ++p) {                                                   \
            _Pragma("unroll")                                                           \
            for (int r = 0; r < 8; ++r) {                                               \
                bf16x8 af = *(const bf16x8*)(arA[p] + (PAR)*6144 + r*576);              \
                AX[r] = __builtin_amdgcn_mfma_f32_16x16x32_bf16(bfr[p],    af, AX[r], 0,0,0); \
                AY[r] = __builtin_amdgcn_mfma_f32_16x16x32_bf16(bfr[5+p],  af, AY[r], 0,0,0); \
                AZ[r] = __builtin_amdgcn_mfma_f32_16x16x32_bf16(bfr[10+p], af, AZ[r], 0,0,0); \
            }                                                                           \
        }                                                                               \
        if ((II) >= 2 && (II) < steps) {                                                \
            _Pragma("unroll")                                                           \
            for (int r = 0; r < 8; ++r) {                                               \
                if (gr[r]) { f32x4 o_ = AZ[r] + bv4; *(f32x4*)(so0 + (long)r*rowE) = o_; } \
            }                                                                           \
        }                                                                               \
        so0 += zsE;                                                                     \
        _Pragma("unroll")                                                               \
        for (int r = 0; r < 8; ++r) AZ[r] = z4;                                         \
    }

    BODY(0, 0, c0, c1, c2)
    BODY(1, 1, c2, c0, c1)
    BODY(2, 0, c1, c2, c0)
    BODY(3, 1, c0, c1, c2)
    BODY(4, 0, c2, c0, c1)
    BODY(5, 1, c1, c2, c0)
#pragma unroll 1
    for (int i = 6; i < steps; i += 6) {
        BODY(i+0, 0, c0, c1, c2)
        BODY(i+1, 1, c2, c0, c1)
        BODY(i+2, 0, c1, c2, c0)
        BODY(i+3, 1, c0, c1, c2)
        BODY(i+4, 0, c2, c0, c1)
        BODY(i+5, 1, c1, c2, c0)
    }
#undef BODY
}

extern "C" void kernel_launch(void* const* d_in, const int* in_sizes, int n_in,
                              void* d_out, int out_size, void* d_ws, size_t ws_size,
                              hipStream_t stream) {
    const float* inp = (const float*)d_in[0];
    const float* wgt = (const float*)d_in[1];
    const float* bia = (const float*)d_in[2];
    float* out = (float*)d_out;
    prep_bfrag<<<dim3((NLVL*3*5*64 + 255)/256), dim3(256), 0, stream>>>(wgt);
    conv_kernel<<<dim3(NBLOCK), dim3(256), 0, stream>>>(inp, bia, out);
}